// Round 11
// baseline (58.434 us; speedup 1.0000x reference)
//
#include <hip/hip_runtime.h>

typedef float v2f __attribute__((ext_vector_type(2)));
typedef short bf16x8 __attribute__((ext_vector_type(8)));
typedef float f32x4 __attribute__((ext_vector_type(4)));

namespace {
constexpr int B   = 8;
constexpr int TQ  = 256;
constexpr int TK  = 256;
constexpr int DQK = 512;
constexpr int DV  = 512;
constexpr int H   = 256;
constexpr int QB  = 4;           // q rows per score block
constexpr int PVQ = 8;           // q rows per pv block
constexpr float C2LOG2E   = 2.8853900817779268f;   // 2*log2(e)
constexpr float NEG2LOG2E = -2.8853900817779268f;
} // namespace

__device__ __forceinline__ uint32_t f2u(float x) { return __builtin_bit_cast(uint32_t, x); }
__device__ __forceinline__ float u2f(uint32_t x) { return __builtin_bit_cast(float, x); }
// pack bf16(x) into low16, bf16(y) into high16 (truncation; lo-term absorbs error)
__device__ __forceinline__ uint32_t pack_hi(float x, float y) {
    return (f2u(y) & 0xFFFF0000u) | (f2u(x) >> 16);
}

// MFMA projections (bf16 hi/lo split: a*b ~ ah*bh + ah*bl + al*bh), fp32 acc.
//  z==0: qpc[b*TQ+q][h]       = exp2( (queries @ Wq)[row][h] * 2log2e )
//  z==1: kpc4[b][h/4][k][h&3] = exp2( (keys    @ Wk)[row][h] * 2log2e )
__global__ __launch_bounds__(256)
void proj_kernel(const float* __restrict__ Q, const float* __restrict__ Kin,
                 const float* __restrict__ Wq, const float* __restrict__ Wk,
                 float* __restrict__ qpc, float* __restrict__ kpc4)
{
    __shared__ short Ahi[4][64][8];   // [kgroup][m][8 bf16] = 4 KB
    __shared__ short Alo[4][64][8];
    __shared__ short Bhi[4][32][8];   // [kgroup][n][8 bf16] = 2 KB
    __shared__ short Blo[4][32][8];

    const bool kside = (blockIdx.z == 1);
    const float* A = kside ? Kin : Q;
    const float* W = kside ? Wk  : Wq;
    const int m0 = blockIdx.x * 64;
    const int n0 = blockIdx.y * 32;
    const int tid = threadIdx.x;

    // staging assignments
    const int am = tid >> 2, ag = tid & 3;          // A: row am, k = ag*8..+7
    const int bk = tid >> 3, bn4 = (tid & 7) * 4;   // B: k row bk, cols bn4..+3
    const float4* aptr = (const float4*)(A + (m0 + am) * DQK) + ag * 2;
    const float*  wptr = W + bk * H + n0 + bn4;

    // wave/frag assignments
    const int w = tid >> 6, l = tid & 63;
    const int wm = (w >> 1) * 32, wn = (w & 1) * 16;
    const int fg = l >> 4;                // k-group
    const int fr = l & 15;                // frag row/col

    // prefetch step 0
    float4 a0 = aptr[0], a1 = aptr[1];
    float4 bv = *(const float4*)wptr;

    f32x4 acc0 = {0.f, 0.f, 0.f, 0.f};
    f32x4 acc1 = {0.f, 0.f, 0.f, 0.f};

    for (int s = 0; s < 16; ++s) {
        __syncthreads();   // previous iteration's frag reads complete
        {
            float ah0 = u2f(f2u(a0.x) & 0xFFFF0000u), ah1 = u2f(f2u(a0.y) & 0xFFFF0000u);
            float ah2 = u2f(f2u(a0.z) & 0xFFFF0000u), ah3 = u2f(f2u(a0.w) & 0xFFFF0000u);
            float ah4 = u2f(f2u(a1.x) & 0xFFFF0000u), ah5 = u2f(f2u(a1.y) & 0xFFFF0000u);
            float ah6 = u2f(f2u(a1.z) & 0xFFFF0000u), ah7 = u2f(f2u(a1.w) & 0xFFFF0000u);
            int4 hw, lw;
            hw.x = (int)pack_hi(a0.x, a0.y); hw.y = (int)pack_hi(a0.z, a0.w);
            hw.z = (int)pack_hi(a1.x, a1.y); hw.w = (int)pack_hi(a1.z, a1.w);
            lw.x = (int)pack_hi(a0.x - ah0, a0.y - ah1);
            lw.y = (int)pack_hi(a0.z - ah2, a0.w - ah3);
            lw.z = (int)pack_hi(a1.x - ah4, a1.y - ah5);
            lw.w = (int)pack_hi(a1.z - ah6, a1.w - ah7);
            *(int4*)&Ahi[ag][am][0] = hw;
            *(int4*)&Alo[ag][am][0] = lw;
            const int g = bk >> 3, slot = bk & 7;
            float bb[4] = {bv.x, bv.y, bv.z, bv.w};
            #pragma unroll
            for (int i = 0; i < 4; ++i) {
                uint32_t u = f2u(bb[i]);
                float hf = u2f(u & 0xFFFF0000u);
                Bhi[g][bn4 + i][slot] = (short)(u >> 16);
                Blo[g][bn4 + i][slot] = (short)(f2u(bb[i] - hf) >> 16);
            }
        }
        __syncthreads();
        if (s < 15) {   // prefetch next K-tile (hides under MFMA chain)
            a0 = aptr[s * 8 + 8];
            a1 = aptr[s * 8 + 9];
            bv = *(const float4*)(wptr + (s + 1) * 32 * H);
        }
        bf16x8 ah_0 = *(const bf16x8*)&Ahi[fg][wm + fr][0];
        bf16x8 ah_1 = *(const bf16x8*)&Ahi[fg][wm + 16 + fr][0];
        bf16x8 al_0 = *(const bf16x8*)&Alo[fg][wm + fr][0];
        bf16x8 al_1 = *(const bf16x8*)&Alo[fg][wm + 16 + fr][0];
        bf16x8 bh   = *(const bf16x8*)&Bhi[fg][wn + fr][0];
        bf16x8 bl   = *(const bf16x8*)&Blo[fg][wn + fr][0];
        acc0 = __builtin_amdgcn_mfma_f32_16x16x32_bf16(ah_0, bh, acc0, 0, 0, 0);
        acc1 = __builtin_amdgcn_mfma_f32_16x16x32_bf16(ah_1, bh, acc1, 0, 0, 0);
        acc0 = __builtin_amdgcn_mfma_f32_16x16x32_bf16(ah_0, bl, acc0, 0, 0, 0);
        acc1 = __builtin_amdgcn_mfma_f32_16x16x32_bf16(ah_1, bl, acc1, 0, 0, 0);
        acc0 = __builtin_amdgcn_mfma_f32_16x16x32_bf16(al_0, bh, acc0, 0, 0, 0);
        acc1 = __builtin_amdgcn_mfma_f32_16x16x32_bf16(al_1, bh, acc1, 0, 0, 0);
    }

    const int col = n0 + wn + fr;
    #pragma unroll
    for (int mi = 0; mi < 2; ++mi) {
        f32x4 acc = mi ? acc1 : acc0;
        #pragma unroll
        for (int r = 0; r < 4; ++r) {
            const int row = m0 + wm + mi * 16 + fg * 4 + r;
            float val = __builtin_amdgcn_exp2f(acc[r] * C2LOG2E);
            if (!kside) {
                qpc[row * H + col] = val;
            } else {
                const int bb2 = row >> 8, kk = row & 255;
                kpc4[((bb2 * (H / 4) + (col >> 2)) * TK + kk) * 4 + (col & 3)] = val;
            }
        }
    }
}

// Scores + unnormalized softmax numerators. Block = (b, qgroup of 4), 512 thr.
// Score: thread = (kpair = tid&127 -> k=2kp,2kp+1; hg = tid>>7 owns 64 h).
//   Inner: r = rcp(eq*ek + 1)  — ONE trans op per element.
// Writes p[(b*TQ+q)*TK+k] = exp2(-2log2e*acc) and rowsum[b*TQ+q] to global;
// PV runs as a separate kernel with its own (QB=8) shape.
__global__ __launch_bounds__(512)
void score_kernel(const float* __restrict__ qpc, const float* __restrict__ kpc4,
                  const float* __restrict__ wv, float* __restrict__ p_out,
                  float* __restrict__ rowsum_g)
{
    __shared__ float qlds[H][QB];        // 4 KB [h][q] (eq, q-major)
    __shared__ float wlds[H];            // 1 KB
    __shared__ float elds[QB][TK];       // 4 KB
    __shared__ float accbuf[4][QB][TK];  // 16 KB score partials

    const int b   = blockIdx.x >> 6;     // 64 q-groups per batch
    const int q0  = (blockIdx.x & 63) * QB;
    const int tid = threadIdx.x;

    for (int i = tid; i < QB * H; i += 512) {
        const int h = i >> 2, q = i & 3;
        qlds[h][q] = qpc[(b * TQ + q0 + q) * H + h];
    }
    if (tid < H) wlds[tid] = wv[tid];
    __syncthreads();

    // ---- score: 2 k-columns, 64 h per thread ----
    {
        const int kp = tid & 127;            // k pair: 2kp, 2kp+1
        const int hg = tid >> 7;             // 0..3
        const int h0 = hg * 64;
        const float4* kc = (const float4*)kpc4 + (b * (H / 4) + (h0 >> 2)) * TK + 2 * kp;
        v2f a01a = {0.f, 0.f}, a23a = {0.f, 0.f};   // k even: q01, q23
        v2f a01b = {0.f, 0.f}, a23b = {0.f, 0.f};   // k odd
        #pragma unroll 4
        for (int h4 = 0; h4 < 16; ++h4) {
            float4 kva4 = kc[h4 * TK];       // ek for k=2kp, 4 h
            float4 kvb4 = kc[h4 * TK + 1];   // ek for k=2kp+1
            #pragma unroll
            for (int j = 0; j < 4; ++j) {
                const int h = h0 + h4 * 4 + j;
                const float ea = (j == 0) ? kva4.x : (j == 1) ? kva4.y : (j == 2) ? kva4.z : kva4.w;
                const float eb = (j == 0) ? kvb4.x : (j == 1) ? kvb4.y : (j == 2) ? kvb4.z : kvb4.w;
                const float wj = wlds[h];
                float4 qa = *(const float4*)&qlds[h][0];   // broadcast eq (4 q)
                v2f q01 = {qa.x, qa.y}, q23 = {qa.z, qa.w};
                v2f ea2 = {ea, ea}, eb2 = {eb, eb}, w2 = {wj, wj};
                v2f one = {1.0f, 1.0f};
                v2f d0a = __builtin_elementwise_fma(q01, ea2, one);  // eq*ek + 1
                v2f d1a = __builtin_elementwise_fma(q23, ea2, one);
                v2f d0b = __builtin_elementwise_fma(q01, eb2, one);
                v2f d1b = __builtin_elementwise_fma(q23, eb2, one);
                v2f r0a, r1a, r0b, r1b;
                r0a.x = __builtin_amdgcn_rcpf(d0a.x);
                r0a.y = __builtin_amdgcn_rcpf(d0a.y);
                r1a.x = __builtin_amdgcn_rcpf(d1a.x);
                r1a.y = __builtin_amdgcn_rcpf(d1a.y);
                r0b.x = __builtin_amdgcn_rcpf(d0b.x);
                r0b.y = __builtin_amdgcn_rcpf(d0b.y);
                r1b.x = __builtin_amdgcn_rcpf(d1b.x);
                r1b.y = __builtin_amdgcn_rcpf(d1b.y);
                a01a = __builtin_elementwise_fma(w2, r0a, a01a);
                a23a = __builtin_elementwise_fma(w2, r1a, a23a);
                a01b = __builtin_elementwise_fma(w2, r0b, a01b);
                a23b = __builtin_elementwise_fma(w2, r1b, a23b);
            }
        }
        accbuf[hg][0][2 * kp]     = a01a.x;
        accbuf[hg][1][2 * kp]     = a01a.y;
        accbuf[hg][2][2 * kp]     = a23a.x;
        accbuf[hg][3][2 * kp]     = a23a.y;
        accbuf[hg][0][2 * kp + 1] = a01b.x;
        accbuf[hg][1][2 * kp + 1] = a01b.y;
        accbuf[hg][2][2 * kp + 1] = a23b.x;
        accbuf[hg][3][2 * kp + 1] = a23b.y;
    }
    __syncthreads();

    // ---- combine h-groups -> p = exp2(-2log2e * acc); write global + elds --
    for (int i = tid; i < QB * TK; i += 512) {
        const int q = i >> 8, kk = i & 255;
        float s = (accbuf[0][q][kk] + accbuf[1][q][kk]) +
                  (accbuf[2][q][kk] + accbuf[3][q][kk]);
        float e = __builtin_amdgcn_exp2f(s * NEG2LOG2E);
        elds[q][kk] = e;
        p_out[(b * TQ + q0 + q) * TK + kk] = e;
    }
    __syncthreads();

    // ---- rowsum: wave w reduces row (w&3); write to global ----
    {
        const int q = (tid >> 6) & 3, lane = tid & 63;
        float4 v = *(const float4*)&elds[q][lane * 4];
        float s = (v.x + v.y) + (v.z + v.w);
        #pragma unroll
        for (int off = 1; off < 64; off <<= 1)
            s += __shfl_xor(s, off);
        if (tid < 256 && lane == 0) rowsum_g[b * TQ + q0 + q] = s;
    }
}

// PV: block = (b, qgroup of 8), 512 threads, thread owns ONE output column.
// Barrier-free main loop; p staged in LDS (broadcast reads), values coalesced.
__global__ __launch_bounds__(512)
void pv_kernel(const float* __restrict__ p, const float* __restrict__ rowsum_g,
               const float* __restrict__ values, float* __restrict__ out)
{
    __shared__ float plds[PVQ][TK];   // 8 KB
    __shared__ float rs[PVQ];

    const int b   = blockIdx.x >> 5;           // 32 q-groups of 8 per batch
    const int q0  = (blockIdx.x & 31) * PVQ;
    const int tid = threadIdx.x;               // output column c

    for (int i = tid; i < PVQ * TK; i += 512)
        plds[i >> 8][i & 255] = p[(b * TQ + q0 + (i >> 8)) * TK + (i & 255)];
    if (tid < PVQ) rs[tid] = rowsum_g[b * TQ + q0 + tid];
    __syncthreads();

    const float* vb = values + b * TK * DV + tid;
    float o[PVQ] = {};
    #pragma unroll 4
    for (int kk = 0; kk < TK; ++kk) {
        float v = vb[kk * DV];
        #pragma unroll
        for (int q = 0; q < PVQ; ++q)
            o[q] = fmaf(plds[q][kk], v, o[q]);
    }
    #pragma unroll
    for (int q = 0; q < PVQ; ++q)
        out[(b * TQ + q0 + q) * DV + tid] = o[q] * __builtin_amdgcn_rcpf(rs[q]);
}

extern "C" void kernel_launch(void* const* d_in, const int* in_sizes, int n_in,
                              void* d_out, int out_size, void* d_ws, size_t ws_size,
                              hipStream_t stream)
{
    const float* queries = (const float*)d_in[0];
    const float* keys    = (const float*)d_in[1];
    const float* values  = (const float*)d_in[2];
    const float* Wq      = (const float*)d_in[3];
    const float* Wk      = (const float*)d_in[4];
    const float* wv      = (const float*)d_in[5];
    float* out    = (float*)d_out;
    float* qpc    = (float*)d_ws;                  // (B*TQ, H)        2 MB (exp'd)
    float* kpc4   = qpc + B * TQ * H;              // (B, H/4, TK, 4)  2 MB (exp'd)
    float* p_ws   = kpc4 + B * H * TK;             // (B*TQ, TK)       2 MB
    float* rs_ws  = p_ws + B * TQ * TK;            // (B*TQ)           8 KB

    dim3 gproj(B * TQ / 64, H / 32, 2);
    proj_kernel<<<gproj, 256, 0, stream>>>(queries, keys, Wq, Wk, qpc, kpc4);
    score_kernel<<<B * (TQ / QB), 512, 0, stream>>>(qpc, kpc4, wv, p_ws, rs_ws);
    pv_kernel<<<B * (TQ / PVQ), 512, 0, stream>>>(p_ws, rs_ws, values, out);
}

// Round 12
// 56.833 us; speedup vs baseline: 1.0282x; 1.0282x over previous
//
#include <hip/hip_runtime.h>

typedef float v2f __attribute__((ext_vector_type(2)));
typedef short bf16x8 __attribute__((ext_vector_type(8)));
typedef float f32x4 __attribute__((ext_vector_type(4)));

namespace {
constexpr int B   = 8;
constexpr int TQ  = 256;
constexpr int TK  = 256;
constexpr int DQK = 512;
constexpr int DV  = 512;
constexpr int H   = 256;
constexpr int QB  = 4;           // q rows per attn block
constexpr float C2LOG2E   = 2.8853900817779268f;   // 2*log2(e)
constexpr float NEG2LOG2E = -2.8853900817779268f;
} // namespace

__device__ __forceinline__ uint32_t f2u(float x) { return __builtin_bit_cast(uint32_t, x); }
__device__ __forceinline__ float u2f(uint32_t x) { return __builtin_bit_cast(float, x); }
// pack bf16(x) into low16, bf16(y) into high16 (truncation; lo-term absorbs error)
__device__ __forceinline__ uint32_t pack_hi(float x, float y) {
    return (f2u(y) & 0xFFFF0000u) | (f2u(x) >> 16);
}

// MFMA projections (bf16 hi/lo split: a*b ~ ah*bh + ah*bl + al*bh), fp32 acc.
//  z==0: qpc[b*TQ+q][h]       = exp2( (queries @ Wq)[row][h] * 2log2e )
//  z==1: kpc4[b][h/4][k][h&3] = exp2( (keys    @ Wk)[row][h] * 2log2e )
__global__ __launch_bounds__(256)
void proj_kernel(const float* __restrict__ Q, const float* __restrict__ Kin,
                 const float* __restrict__ Wq, const float* __restrict__ Wk,
                 float* __restrict__ qpc, float* __restrict__ kpc4)
{
    __shared__ short Ahi[4][64][8];   // [kgroup][m][8 bf16] = 4 KB
    __shared__ short Alo[4][64][8];
    __shared__ short Bhi[4][32][8];   // [kgroup][n][8 bf16] = 2 KB
    __shared__ short Blo[4][32][8];

    const bool kside = (blockIdx.z == 1);
    const float* A = kside ? Kin : Q;
    const float* W = kside ? Wk  : Wq;
    const int m0 = blockIdx.x * 64;
    const int n0 = blockIdx.y * 32;
    const int tid = threadIdx.x;

    // staging assignments
    const int am = tid >> 2, ag = tid & 3;          // A: row am, k = ag*8..+7
    const int bk = tid >> 3, bn4 = (tid & 7) * 4;   // B: k row bk, cols bn4..+3
    const float4* aptr = (const float4*)(A + (m0 + am) * DQK) + ag * 2;
    const float*  wptr = W + bk * H + n0 + bn4;

    // wave/frag assignments
    const int w = tid >> 6, l = tid & 63;
    const int wm = (w >> 1) * 32, wn = (w & 1) * 16;
    const int fg = l >> 4;                // k-group
    const int fr = l & 15;                // frag row/col

    // prefetch step 0
    float4 a0 = aptr[0], a1 = aptr[1];
    float4 bv = *(const float4*)wptr;

    f32x4 acc0 = {0.f, 0.f, 0.f, 0.f};
    f32x4 acc1 = {0.f, 0.f, 0.f, 0.f};

    for (int s = 0; s < 16; ++s) {
        __syncthreads();   // previous iteration's frag reads complete
        {
            float ah0 = u2f(f2u(a0.x) & 0xFFFF0000u), ah1 = u2f(f2u(a0.y) & 0xFFFF0000u);
            float ah2 = u2f(f2u(a0.z) & 0xFFFF0000u), ah3 = u2f(f2u(a0.w) & 0xFFFF0000u);
            float ah4 = u2f(f2u(a1.x) & 0xFFFF0000u), ah5 = u2f(f2u(a1.y) & 0xFFFF0000u);
            float ah6 = u2f(f2u(a1.z) & 0xFFFF0000u), ah7 = u2f(f2u(a1.w) & 0xFFFF0000u);
            int4 hw, lw;
            hw.x = (int)pack_hi(a0.x, a0.y); hw.y = (int)pack_hi(a0.z, a0.w);
            hw.z = (int)pack_hi(a1.x, a1.y); hw.w = (int)pack_hi(a1.z, a1.w);
            lw.x = (int)pack_hi(a0.x - ah0, a0.y - ah1);
            lw.y = (int)pack_hi(a0.z - ah2, a0.w - ah3);
            lw.z = (int)pack_hi(a1.x - ah4, a1.y - ah5);
            lw.w = (int)pack_hi(a1.z - ah6, a1.w - ah7);
            *(int4*)&Ahi[ag][am][0] = hw;
            *(int4*)&Alo[ag][am][0] = lw;
            const int g = bk >> 3, slot = bk & 7;
            float bb[4] = {bv.x, bv.y, bv.z, bv.w};
            #pragma unroll
            for (int i = 0; i < 4; ++i) {
                uint32_t u = f2u(bb[i]);
                float hf = u2f(u & 0xFFFF0000u);
                Bhi[g][bn4 + i][slot] = (short)(u >> 16);
                Blo[g][bn4 + i][slot] = (short)(f2u(bb[i] - hf) >> 16);
            }
        }
        __syncthreads();
        if (s < 15) {   // prefetch next K-tile (hides under MFMA chain)
            a0 = aptr[s * 8 + 8];
            a1 = aptr[s * 8 + 9];
            bv = *(const float4*)(wptr + (s + 1) * 32 * H);
        }
        bf16x8 ah_0 = *(const bf16x8*)&Ahi[fg][wm + fr][0];
        bf16x8 ah_1 = *(const bf16x8*)&Ahi[fg][wm + 16 + fr][0];
        bf16x8 al_0 = *(const bf16x8*)&Alo[fg][wm + fr][0];
        bf16x8 al_1 = *(const bf16x8*)&Alo[fg][wm + 16 + fr][0];
        bf16x8 bh   = *(const bf16x8*)&Bhi[fg][wn + fr][0];
        bf16x8 bl   = *(const bf16x8*)&Blo[fg][wn + fr][0];
        acc0 = __builtin_amdgcn_mfma_f32_16x16x32_bf16(ah_0, bh, acc0, 0, 0, 0);
        acc1 = __builtin_amdgcn_mfma_f32_16x16x32_bf16(ah_1, bh, acc1, 0, 0, 0);
        acc0 = __builtin_amdgcn_mfma_f32_16x16x32_bf16(ah_0, bl, acc0, 0, 0, 0);
        acc1 = __builtin_amdgcn_mfma_f32_16x16x32_bf16(ah_1, bl, acc1, 0, 0, 0);
        acc0 = __builtin_amdgcn_mfma_f32_16x16x32_bf16(al_0, bh, acc0, 0, 0, 0);
        acc1 = __builtin_amdgcn_mfma_f32_16x16x32_bf16(al_1, bh, acc1, 0, 0, 0);
    }

    const int col = n0 + wn + fr;
    #pragma unroll
    for (int mi = 0; mi < 2; ++mi) {
        f32x4 acc = mi ? acc1 : acc0;
        #pragma unroll
        for (int r = 0; r < 4; ++r) {
            const int row = m0 + wm + mi * 16 + fg * 4 + r;
            float val = __builtin_amdgcn_exp2f(acc[r] * C2LOG2E);
            if (!kside) {
                qpc[row * H + col] = val;
            } else {
                const int bb2 = row >> 8, kk = row & 255;
                kpc4[((bb2 * (H / 4) + (col >> 2)) * TK + kk) * 4 + (col & 3)] = val;
            }
        }
    }
}

// Fused scores + softmax + PV. Block = (b, qgroup of 4), 512 threads, grid 512.
// 3 internal barriers: load | score->accbuf | combine(pT + fused rowsum) | PV.
// Score: thread = (kpair = tid&127 -> k=2kp,2kp+1; hg = tid>>7 owns 64 h);
//   inner: r = rcp(eq*ek + 1) — one trans op per element (exp2 precomputed).
// Softmax without max-subtraction (logits bounded; overflow limit exact: rcp->0).
// PV: thread owns ONE output column; per k: 1 coalesced load + 1 pT float4
//   broadcast + 4 fma; normalize at store.
__global__ __launch_bounds__(512)
void attn_kernel(const float* __restrict__ qpc, const float* __restrict__ kpc4,
                 const float* __restrict__ wv, const float* __restrict__ values,
                 float* __restrict__ out)
{
    __shared__ float qlds[H][QB];        // 4 KB [h][q] (eq, q-major)
    __shared__ float wlds[H];            // 1 KB
    __shared__ float accbuf[4][QB][TK];  // 16 KB score partials
    __shared__ float pT[TK][QB];         // 4 KB p transposed
    __shared__ float rowsum[QB];

    const int b   = blockIdx.x >> 6;     // 64 q-groups per batch
    const int q0  = (blockIdx.x & 63) * QB;
    const int tid = threadIdx.x;

    for (int i = tid; i < QB * H; i += 512) {
        const int h = i >> 2, q = i & 3;
        qlds[h][q] = qpc[(b * TQ + q0 + q) * H + h];
    }
    if (tid < H) wlds[tid] = wv[tid];
    if (tid < QB) rowsum[tid] = 0.0f;
    __syncthreads();

    // ---- score: 2 k-columns, 64 h per thread (identical to R10) ----
    {
        const int kp = tid & 127;            // k pair: 2kp, 2kp+1
        const int hg = tid >> 7;             // 0..3
        const int h0 = hg * 64;
        const float4* kc = (const float4*)kpc4 + (b * (H / 4) + (h0 >> 2)) * TK + 2 * kp;
        v2f a01a = {0.f, 0.f}, a23a = {0.f, 0.f};   // k even: q01, q23
        v2f a01b = {0.f, 0.f}, a23b = {0.f, 0.f};   // k odd
        #pragma unroll 4
        for (int h4 = 0; h4 < 16; ++h4) {
            float4 kva4 = kc[h4 * TK];       // ek for k=2kp, 4 h
            float4 kvb4 = kc[h4 * TK + 1];   // ek for k=2kp+1
            #pragma unroll
            for (int j = 0; j < 4; ++j) {
                const int h = h0 + h4 * 4 + j;
                const float ea = (j == 0) ? kva4.x : (j == 1) ? kva4.y : (j == 2) ? kva4.z : kva4.w;
                const float eb = (j == 0) ? kvb4.x : (j == 1) ? kvb4.y : (j == 2) ? kvb4.z : kvb4.w;
                const float wj = wlds[h];
                float4 qa = *(const float4*)&qlds[h][0];   // broadcast eq (4 q)
                v2f q01 = {qa.x, qa.y}, q23 = {qa.z, qa.w};
                v2f ea2 = {ea, ea}, eb2 = {eb, eb}, w2 = {wj, wj};
                v2f one = {1.0f, 1.0f};
                v2f d0a = __builtin_elementwise_fma(q01, ea2, one);  // eq*ek + 1
                v2f d1a = __builtin_elementwise_fma(q23, ea2, one);
                v2f d0b = __builtin_elementwise_fma(q01, eb2, one);
                v2f d1b = __builtin_elementwise_fma(q23, eb2, one);
                v2f r0a, r1a, r0b, r1b;
                r0a.x = __builtin_amdgcn_rcpf(d0a.x);
                r0a.y = __builtin_amdgcn_rcpf(d0a.y);
                r1a.x = __builtin_amdgcn_rcpf(d1a.x);
                r1a.y = __builtin_amdgcn_rcpf(d1a.y);
                r0b.x = __builtin_amdgcn_rcpf(d0b.x);
                r0b.y = __builtin_amdgcn_rcpf(d0b.y);
                r1b.x = __builtin_amdgcn_rcpf(d1b.x);
                r1b.y = __builtin_amdgcn_rcpf(d1b.y);
                a01a = __builtin_elementwise_fma(w2, r0a, a01a);
                a23a = __builtin_elementwise_fma(w2, r1a, a23a);
                a01b = __builtin_elementwise_fma(w2, r0b, a01b);
                a23b = __builtin_elementwise_fma(w2, r1b, a23b);
            }
        }
        accbuf[hg][0][2 * kp]     = a01a.x;
        accbuf[hg][1][2 * kp]     = a01a.y;
        accbuf[hg][2][2 * kp]     = a23a.x;
        accbuf[hg][3][2 * kp]     = a23a.y;
        accbuf[hg][0][2 * kp + 1] = a01b.x;
        accbuf[hg][1][2 * kp + 1] = a01b.y;
        accbuf[hg][2][2 * kp + 1] = a23b.x;
        accbuf[hg][3][2 * kp + 1] = a23b.y;
    }
    __syncthreads();

    // ---- combine -> pT[kk][q] = exp2(-2log2e*acc); rowsum fused in-wave ----
    // entry i: kk = i>>2, q = i&3. q = tid&3 is invariant across both iters;
    // butterfly over xor 4/8/16/32 sums the 16 lanes sharing lane&3, then
    // lanes 0-3 add their q's partial (8 waves x 2 iters x 4 adds = 64 atomics).
    for (int i = tid; i < QB * TK; i += 512) {
        const int kk = i >> 2, q = i & 3;
        float s = (accbuf[0][q][kk] + accbuf[1][q][kk]) +
                  (accbuf[2][q][kk] + accbuf[3][q][kk]);
        float e = __builtin_amdgcn_exp2f(s * NEG2LOG2E);
        pT[kk][q] = e;
        float r = e;
        r += __shfl_xor(r, 4);
        r += __shfl_xor(r, 8);
        r += __shfl_xor(r, 16);
        r += __shfl_xor(r, 32);
        if ((tid & 63) < 4) atomicAdd(&rowsum[tid & 63], r);
    }
    __syncthreads();

    // ---- PV: thread owns column c; per k: 1 load + 1 b128 broadcast + 4 fma --
    {
        const int c = tid;
        const float* vb = values + b * TK * DV + c;
        float o0 = 0.f, o1 = 0.f, o2 = 0.f, o3 = 0.f;
        #pragma unroll 4
        for (int kk = 0; kk < TK; ++kk) {
            float v = vb[kk * DV];
            float4 p4 = *(const float4*)&pT[kk][0];
            o0 = fmaf(p4.x, v, o0);
            o1 = fmaf(p4.y, v, o1);
            o2 = fmaf(p4.z, v, o2);
            o3 = fmaf(p4.w, v, o3);
        }
        float* ob = out + (b * TQ + q0) * DV + c;
        ob[0 * DV] = o0 * __builtin_amdgcn_rcpf(rowsum[0]);
        ob[1 * DV] = o1 * __builtin_amdgcn_rcpf(rowsum[1]);
        ob[2 * DV] = o2 * __builtin_amdgcn_rcpf(rowsum[2]);
        ob[3 * DV] = o3 * __builtin_amdgcn_rcpf(rowsum[3]);
    }
}

extern "C" void kernel_launch(void* const* d_in, const int* in_sizes, int n_in,
                              void* d_out, int out_size, void* d_ws, size_t ws_size,
                              hipStream_t stream)
{
    const float* queries = (const float*)d_in[0];
    const float* keys    = (const float*)d_in[1];
    const float* values  = (const float*)d_in[2];
    const float* Wq      = (const float*)d_in[3];
    const float* Wk      = (const float*)d_in[4];
    const float* wv      = (const float*)d_in[5];
    float* out  = (float*)d_out;
    float* qpc  = (float*)d_ws;                    // (B*TQ, H)        2 MB (exp'd)
    float* kpc4 = qpc + B * TQ * H;                // (B, H/4, TK, 4)  2 MB (exp'd)

    dim3 gproj(B * TQ / 64, H / 32, 2);
    proj_kernel<<<gproj, 256, 0, stream>>>(queries, keys, Wq, Wk, qpc, kpc4);
    attn_kernel<<<B * (TQ / QB), 512, 0, stream>>>(qpc, kpc4, wv, values, out);
}

// Round 13
// 54.919 us; speedup vs baseline: 1.0640x; 1.0349x over previous
//
#include <hip/hip_runtime.h>

typedef float v2f __attribute__((ext_vector_type(2)));
typedef short bf16x8 __attribute__((ext_vector_type(8)));
typedef float f32x4 __attribute__((ext_vector_type(4)));

namespace {
constexpr int B   = 8;
constexpr int TQ  = 256;
constexpr int TK  = 256;
constexpr int DQK = 512;
constexpr int DV  = 512;
constexpr int H   = 256;
constexpr int QB  = 4;           // q rows per attn block
constexpr float C2LOG2E   = 2.8853900817779268f;   // 2*log2(e)
constexpr float NEG2LOG2E = -2.8853900817779268f;
} // namespace

__device__ __forceinline__ uint32_t f2u(float x) { return __builtin_bit_cast(uint32_t, x); }
__device__ __forceinline__ float u2f(uint32_t x) { return __builtin_bit_cast(float, x); }
__device__ __forceinline__ uint32_t pack_hi(float x, float y) {
    return (f2u(y) & 0xFFFF0000u) | (f2u(x) >> 16);
}

// MFMA projections (bf16 hi/lo split), identical to R10.
__global__ __launch_bounds__(256)
void proj_kernel(const float* __restrict__ Q, const float* __restrict__ Kin,
                 const float* __restrict__ Wq, const float* __restrict__ Wk,
                 float* __restrict__ qpc, float* __restrict__ kpc4)
{
    __shared__ short Ahi[4][64][8];
    __shared__ short Alo[4][64][8];
    __shared__ short Bhi[4][32][8];
    __shared__ short Blo[4][32][8];

    const bool kside = (blockIdx.z == 1);
    const float* A = kside ? Kin : Q;
    const float* W = kside ? Wk  : Wq;
    const int m0 = blockIdx.x * 64;
    const int n0 = blockIdx.y * 32;
    const int tid = threadIdx.x;

    const int am = tid >> 2, ag = tid & 3;
    const int bk = tid >> 3, bn4 = (tid & 7) * 4;
    const float4* aptr = (const float4*)(A + (m0 + am) * DQK) + ag * 2;
    const float*  wptr = W + bk * H + n0 + bn4;

    const int w = tid >> 6, l = tid & 63;
    const int wm = (w >> 1) * 32, wn = (w & 1) * 16;
    const int fg = l >> 4;
    const int fr = l & 15;

    float4 a0 = aptr[0], a1 = aptr[1];
    float4 bv = *(const float4*)wptr;

    f32x4 acc0 = {0.f, 0.f, 0.f, 0.f};
    f32x4 acc1 = {0.f, 0.f, 0.f, 0.f};

    for (int s = 0; s < 16; ++s) {
        __syncthreads();
        {
            float ah0 = u2f(f2u(a0.x) & 0xFFFF0000u), ah1 = u2f(f2u(a0.y) & 0xFFFF0000u);
            float ah2 = u2f(f2u(a0.z) & 0xFFFF0000u), ah3 = u2f(f2u(a0.w) & 0xFFFF0000u);
            float ah4 = u2f(f2u(a1.x) & 0xFFFF0000u), ah5 = u2f(f2u(a1.y) & 0xFFFF0000u);
            float ah6 = u2f(f2u(a1.z) & 0xFFFF0000u), ah7 = u2f(f2u(a1.w) & 0xFFFF0000u);
            int4 hw, lw;
            hw.x = (int)pack_hi(a0.x, a0.y); hw.y = (int)pack_hi(a0.z, a0.w);
            hw.z = (int)pack_hi(a1.x, a1.y); hw.w = (int)pack_hi(a1.z, a1.w);
            lw.x = (int)pack_hi(a0.x - ah0, a0.y - ah1);
            lw.y = (int)pack_hi(a0.z - ah2, a0.w - ah3);
            lw.z = (int)pack_hi(a1.x - ah4, a1.y - ah5);
            lw.w = (int)pack_hi(a1.z - ah6, a1.w - ah7);
            *(int4*)&Ahi[ag][am][0] = hw;
            *(int4*)&Alo[ag][am][0] = lw;
            const int g = bk >> 3, slot = bk & 7;
            float bb[4] = {bv.x, bv.y, bv.z, bv.w};
            #pragma unroll
            for (int i = 0; i < 4; ++i) {
                uint32_t u = f2u(bb[i]);
                float hf = u2f(u & 0xFFFF0000u);
                Bhi[g][bn4 + i][slot] = (short)(u >> 16);
                Blo[g][bn4 + i][slot] = (short)(f2u(bb[i] - hf) >> 16);
            }
        }
        __syncthreads();
        if (s < 15) {
            a0 = aptr[s * 8 + 8];
            a1 = aptr[s * 8 + 9];
            bv = *(const float4*)(wptr + (s + 1) * 32 * H);
        }
        bf16x8 ah_0 = *(const bf16x8*)&Ahi[fg][wm + fr][0];
        bf16x8 ah_1 = *(const bf16x8*)&Ahi[fg][wm + 16 + fr][0];
        bf16x8 al_0 = *(const bf16x8*)&Alo[fg][wm + fr][0];
        bf16x8 al_1 = *(const bf16x8*)&Alo[fg][wm + 16 + fr][0];
        bf16x8 bh   = *(const bf16x8*)&Bhi[fg][wn + fr][0];
        bf16x8 bl   = *(const bf16x8*)&Blo[fg][wn + fr][0];
        acc0 = __builtin_amdgcn_mfma_f32_16x16x32_bf16(ah_0, bh, acc0, 0, 0, 0);
        acc1 = __builtin_amdgcn_mfma_f32_16x16x32_bf16(ah_1, bh, acc1, 0, 0, 0);
        acc0 = __builtin_amdgcn_mfma_f32_16x16x32_bf16(ah_0, bl, acc0, 0, 0, 0);
        acc1 = __builtin_amdgcn_mfma_f32_16x16x32_bf16(ah_1, bl, acc1, 0, 0, 0);
        acc0 = __builtin_amdgcn_mfma_f32_16x16x32_bf16(al_0, bh, acc0, 0, 0, 0);
        acc1 = __builtin_amdgcn_mfma_f32_16x16x32_bf16(al_1, bh, acc1, 0, 0, 0);
    }

    const int col = n0 + wn + fr;
    #pragma unroll
    for (int mi = 0; mi < 2; ++mi) {
        f32x4 acc = mi ? acc1 : acc0;
        #pragma unroll
        for (int r = 0; r < 4; ++r) {
            const int row = m0 + wm + mi * 16 + fg * 4 + r;
            float val = __builtin_amdgcn_exp2f(acc[r] * C2LOG2E);
            if (!kside) {
                qpc[row * H + col] = val;
            } else {
                const int bb2 = row >> 8, kk = row & 255;
                kpc4[((bb2 * (H / 4) + (col >> 2)) * TK + kk) * 4 + (col & 3)] = val;
            }
        }
    }
}

// Fused scores + partial softmax + partial PV over a K-HALF.
// Block = (b, qgroup of 4, khalf), 512 threads, grid 1024 = 4 blocks/CU.
// Score: thread = (kp = tid&63 -> k = kh*128+2kp(+1); hg = tid>>6 owns 32 h);
//   inner identical to R10: r = rcp(eq*ek + 1), one trans op per element.
// Writes UNNORMALIZED PV partial to opart[kh] and partial rowsum to rs_g
// (indexed by khalf — no atomics; epilogue combines; 2-way fp32 sums exact).
__global__ __launch_bounds__(512, 8)
void attn_kernel(const float* __restrict__ qpc, const float* __restrict__ kpc4,
                 const float* __restrict__ wv, const float* __restrict__ values,
                 float* __restrict__ opart, float* __restrict__ rs_g)
{
    __shared__ float qlds[H][QB];        // 4 KB [h][q] (eq)
    __shared__ float wlds[H];            // 1 KB
    __shared__ float accbuf[8][QB][128]; // 16 KB score partials (8 h-groups)
    __shared__ float elds[QB][128];      // 2 KB p for this k-half

    const int bid = blockIdx.x;
    const int b   = bid >> 7;
    const int qg  = (bid >> 1) & 63;
    const int kh  = bid & 1;
    const int q0  = qg * QB;
    const int tid = threadIdx.x;

    for (int i = tid; i < QB * H; i += 512) {
        const int h = i >> 2, q = i & 3;
        qlds[h][q] = qpc[(b * TQ + q0 + q) * H + h];
    }
    if (tid < H) wlds[tid] = wv[tid];
    __syncthreads();

    // ---- score: 2 k-columns (within half), 32 h per thread ----
    {
        const int kp = tid & 63;             // k pair within half
        const int hg = tid >> 6;             // 0..7, 32 h each
        const int h0 = hg * 32;
        const float4* kc = (const float4*)kpc4 + (b * (H / 4) + hg * 8) * TK
                           + (kh * 128 + 2 * kp);
        v2f a01a = {0.f, 0.f}, a23a = {0.f, 0.f};   // k even: q01, q23
        v2f a01b = {0.f, 0.f}, a23b = {0.f, 0.f};   // k odd
        #pragma unroll 4
        for (int h4 = 0; h4 < 8; ++h4) {
            float4 kva4 = kc[h4 * TK];       // ek for k even, 4 h
            float4 kvb4 = kc[h4 * TK + 1];   // ek for k odd
            float4 w4 = *(const float4*)&wlds[h0 + h4 * 4];
            #pragma unroll
            for (int j = 0; j < 4; ++j) {
                const int h = h0 + h4 * 4 + j;
                const float ea = (j == 0) ? kva4.x : (j == 1) ? kva4.y : (j == 2) ? kva4.z : kva4.w;
                const float eb = (j == 0) ? kvb4.x : (j == 1) ? kvb4.y : (j == 2) ? kvb4.z : kvb4.w;
                const float wj = (j == 0) ? w4.x  : (j == 1) ? w4.y  : (j == 2) ? w4.z  : w4.w;
                float4 qa = *(const float4*)&qlds[h][0];   // broadcast eq (4 q)
                v2f q01 = {qa.x, qa.y}, q23 = {qa.z, qa.w};
                v2f ea2 = {ea, ea}, eb2 = {eb, eb}, w2 = {wj, wj};
                v2f one = {1.0f, 1.0f};
                v2f d0a = __builtin_elementwise_fma(q01, ea2, one);  // eq*ek + 1
                v2f d1a = __builtin_elementwise_fma(q23, ea2, one);
                v2f d0b = __builtin_elementwise_fma(q01, eb2, one);
                v2f d1b = __builtin_elementwise_fma(q23, eb2, one);
                v2f r0a, r1a, r0b, r1b;
                r0a.x = __builtin_amdgcn_rcpf(d0a.x);
                r0a.y = __builtin_amdgcn_rcpf(d0a.y);
                r1a.x = __builtin_amdgcn_rcpf(d1a.x);
                r1a.y = __builtin_amdgcn_rcpf(d1a.y);
                r0b.x = __builtin_amdgcn_rcpf(d0b.x);
                r0b.y = __builtin_amdgcn_rcpf(d0b.y);
                r1b.x = __builtin_amdgcn_rcpf(d1b.x);
                r1b.y = __builtin_amdgcn_rcpf(d1b.y);
                a01a = __builtin_elementwise_fma(w2, r0a, a01a);
                a23a = __builtin_elementwise_fma(w2, r1a, a23a);
                a01b = __builtin_elementwise_fma(w2, r0b, a01b);
                a23b = __builtin_elementwise_fma(w2, r1b, a23b);
            }
        }
        accbuf[hg][0][2 * kp]     = a01a.x;
        accbuf[hg][1][2 * kp]     = a01a.y;
        accbuf[hg][2][2 * kp]     = a23a.x;
        accbuf[hg][3][2 * kp]     = a23a.y;
        accbuf[hg][0][2 * kp + 1] = a01b.x;
        accbuf[hg][1][2 * kp + 1] = a01b.y;
        accbuf[hg][2][2 * kp + 1] = a23b.x;
        accbuf[hg][3][2 * kp + 1] = a23b.y;
    }
    __syncthreads();

    // ---- combine 8 h-groups -> p = exp2(-2log2e*acc); one entry/thread ----
    {
        const int q = tid >> 7, kl = tid & 127;
        float s = ((accbuf[0][q][kl] + accbuf[1][q][kl]) +
                   (accbuf[2][q][kl] + accbuf[3][q][kl])) +
                  ((accbuf[4][q][kl] + accbuf[5][q][kl]) +
                   (accbuf[6][q][kl] + accbuf[7][q][kl]));
        elds[q][kl] = __builtin_amdgcn_exp2f(s * NEG2LOG2E);
    }
    __syncthreads();

    // ---- partial rowsum (waves 0-3; global write, consumed by epilogue) ----
    {
        const int wave = tid >> 6, lane = tid & 63;
        if (wave < QB) {
            float s = elds[wave][lane] + elds[wave][lane + 64];
            #pragma unroll
            for (int off = 1; off < 64; off <<= 1)
                s += __shfl_xor(s, off);
            if (lane == 0) rs_g[(b * TQ + q0 + wave) * 2 + kh] = s;
        }
    }

    // ---- partial PV: thread owns column c; 128 k of this half ----
    {
        const int c = tid;
        const float* vb = values + (b * TK + kh * 128) * DV + c;
        float o0 = 0.f, o1 = 0.f, o2 = 0.f, o3 = 0.f;
        #pragma unroll 4
        for (int kk = 0; kk < 128; ++kk) {
            float v = vb[kk * DV];
            o0 = fmaf(elds[0][kk], v, o0);
            o1 = fmaf(elds[1][kk], v, o1);
            o2 = fmaf(elds[2][kk], v, o2);
            o3 = fmaf(elds[3][kk], v, o3);
        }
        float* ob = opart + kh * (B * TQ * DV) + (b * TQ + q0) * DV + c;
        ob[0 * DV] = o0;
        ob[1 * DV] = o1;
        ob[2 * DV] = o2;
        ob[3 * DV] = o3;
    }
}

// out = (opart0 + opart1) * rcp(rs0 + rs1), float4 per thread.
__global__ __launch_bounds__(256)
void epilogue_kernel(const float* __restrict__ opart, const float* __restrict__ rs_g,
                     float* __restrict__ out)
{
    const int idx4 = blockIdx.x * 256 + threadIdx.x;     // f4 index, 262144 total
    const int row  = idx4 >> 7;                          // 128 f4 per row (DV=512)
    float rs = rs_g[2 * row] + rs_g[2 * row + 1];
    float inv = __builtin_amdgcn_rcpf(rs);
    const float4* o0 = (const float4*)opart;
    const float4* o1 = (const float4*)(opart + B * TQ * DV);
    float4 a = o0[idx4], bq = o1[idx4];
    float4 r;
    r.x = (a.x + bq.x) * inv;
    r.y = (a.y + bq.y) * inv;
    r.z = (a.z + bq.z) * inv;
    r.w = (a.w + bq.w) * inv;
    ((float4*)out)[idx4] = r;
}

extern "C" void kernel_launch(void* const* d_in, const int* in_sizes, int n_in,
                              void* d_out, int out_size, void* d_ws, size_t ws_size,
                              hipStream_t stream)
{
    const float* queries = (const float*)d_in[0];
    const float* keys    = (const float*)d_in[1];
    const float* values  = (const float*)d_in[2];
    const float* Wq      = (const float*)d_in[3];
    const float* Wk      = (const float*)d_in[4];
    const float* wv      = (const float*)d_in[5];
    float* out   = (float*)d_out;
    float* qpc   = (float*)d_ws;                   // (B*TQ, H)         2 MB (exp'd)
    float* kpc4  = qpc + B * TQ * H;               // (B, H/4, TK, 4)   2 MB (exp'd)
    float* opart = kpc4 + B * H * TK;              // [2][B*TQ, DV]     8 MB
    float* rs_g  = opart + 2 * B * TQ * DV;        // (B*TQ, 2)        16 KB

    dim3 gproj(B * TQ / 64, H / 32, 2);
    proj_kernel<<<gproj, 256, 0, stream>>>(queries, keys, Wq, Wk, qpc, kpc4);
    attn_kernel<<<B * (TQ / QB) * 2, 512, 0, stream>>>(qpc, kpc4, wv, values, opart, rs_g);
    epilogue_kernel<<<B * TQ * DV / 4 / 256, 256, 0, stream>>>(opart, rs_g, out);
}

// Round 14
// 49.835 us; speedup vs baseline: 1.1726x; 1.1020x over previous
//
#include <hip/hip_runtime.h>

typedef float v2f __attribute__((ext_vector_type(2)));
typedef short bf16x8 __attribute__((ext_vector_type(8)));
typedef float f32x4 __attribute__((ext_vector_type(4)));

namespace {
constexpr int B   = 8;
constexpr int TQ  = 256;
constexpr int TK  = 256;
constexpr int DQK = 512;
constexpr int DV  = 512;
constexpr int H   = 256;
constexpr int QB  = 4;           // q rows per attn block
constexpr float C2LOG2E   = 2.8853900817779268f;   // 2*log2(e)
constexpr float NEG2LOG2E = -2.8853900817779268f;
} // namespace

__device__ __forceinline__ uint32_t f2u(float x) { return __builtin_bit_cast(uint32_t, x); }
__device__ __forceinline__ float u2f(uint32_t x) { return __builtin_bit_cast(float, x); }
__device__ __forceinline__ uint32_t pack_hi(float x, float y) {
    return (f2u(y) & 0xFFFF0000u) | (f2u(x) >> 16);
}

// MFMA projections (bf16 hi/lo split), identical to R10/R13.
__global__ __launch_bounds__(256)
void proj_kernel(const float* __restrict__ Q, const float* __restrict__ Kin,
                 const float* __restrict__ Wq, const float* __restrict__ Wk,
                 float* __restrict__ qpc, float* __restrict__ kpc4)
{
    __shared__ short Ahi[4][64][8];
    __shared__ short Alo[4][64][8];
    __shared__ short Bhi[4][32][8];
    __shared__ short Blo[4][32][8];

    const bool kside = (blockIdx.z == 1);
    const float* A = kside ? Kin : Q;
    const float* W = kside ? Wk  : Wq;
    const int m0 = blockIdx.x * 64;
    const int n0 = blockIdx.y * 32;
    const int tid = threadIdx.x;

    const int am = tid >> 2, ag = tid & 3;
    const int bk = tid >> 3, bn4 = (tid & 7) * 4;
    const float4* aptr = (const float4*)(A + (m0 + am) * DQK) + ag * 2;
    const float*  wptr = W + bk * H + n0 + bn4;

    const int w = tid >> 6, l = tid & 63;
    const int wm = (w >> 1) * 32, wn = (w & 1) * 16;
    const int fg = l >> 4;
    const int fr = l & 15;

    float4 a0 = aptr[0], a1 = aptr[1];
    float4 bv = *(const float4*)wptr;

    f32x4 acc0 = {0.f, 0.f, 0.f, 0.f};
    f32x4 acc1 = {0.f, 0.f, 0.f, 0.f};

    for (int s = 0; s < 16; ++s) {
        __syncthreads();
        {
            float ah0 = u2f(f2u(a0.x) & 0xFFFF0000u), ah1 = u2f(f2u(a0.y) & 0xFFFF0000u);
            float ah2 = u2f(f2u(a0.z) & 0xFFFF0000u), ah3 = u2f(f2u(a0.w) & 0xFFFF0000u);
            float ah4 = u2f(f2u(a1.x) & 0xFFFF0000u), ah5 = u2f(f2u(a1.y) & 0xFFFF0000u);
            float ah6 = u2f(f2u(a1.z) & 0xFFFF0000u), ah7 = u2f(f2u(a1.w) & 0xFFFF0000u);
            int4 hw, lw;
            hw.x = (int)pack_hi(a0.x, a0.y); hw.y = (int)pack_hi(a0.z, a0.w);
            hw.z = (int)pack_hi(a1.x, a1.y); hw.w = (int)pack_hi(a1.z, a1.w);
            lw.x = (int)pack_hi(a0.x - ah0, a0.y - ah1);
            lw.y = (int)pack_hi(a0.z - ah2, a0.w - ah3);
            lw.z = (int)pack_hi(a1.x - ah4, a1.y - ah5);
            lw.w = (int)pack_hi(a1.z - ah6, a1.w - ah7);
            *(int4*)&Ahi[ag][am][0] = hw;
            *(int4*)&Alo[ag][am][0] = lw;
            const int g = bk >> 3, slot = bk & 7;
            float bb[4] = {bv.x, bv.y, bv.z, bv.w};
            #pragma unroll
            for (int i = 0; i < 4; ++i) {
                uint32_t u = f2u(bb[i]);
                float hf = u2f(u & 0xFFFF0000u);
                Bhi[g][bn4 + i][slot] = (short)(u >> 16);
                Blo[g][bn4 + i][slot] = (short)(f2u(bb[i] - hf) >> 16);
            }
        }
        __syncthreads();
        if (s < 15) {
            a0 = aptr[s * 8 + 8];
            a1 = aptr[s * 8 + 9];
            bv = *(const float4*)(wptr + (s + 1) * 32 * H);
        }
        bf16x8 ah_0 = *(const bf16x8*)&Ahi[fg][wm + fr][0];
        bf16x8 ah_1 = *(const bf16x8*)&Ahi[fg][wm + 16 + fr][0];
        bf16x8 al_0 = *(const bf16x8*)&Alo[fg][wm + fr][0];
        bf16x8 al_1 = *(const bf16x8*)&Alo[fg][wm + 16 + fr][0];
        bf16x8 bh   = *(const bf16x8*)&Bhi[fg][wn + fr][0];
        bf16x8 bl   = *(const bf16x8*)&Blo[fg][wn + fr][0];
        acc0 = __builtin_amdgcn_mfma_f32_16x16x32_bf16(ah_0, bh, acc0, 0, 0, 0);
        acc1 = __builtin_amdgcn_mfma_f32_16x16x32_bf16(ah_1, bh, acc1, 0, 0, 0);
        acc0 = __builtin_amdgcn_mfma_f32_16x16x32_bf16(ah_0, bl, acc0, 0, 0, 0);
        acc1 = __builtin_amdgcn_mfma_f32_16x16x32_bf16(ah_1, bl, acc1, 0, 0, 0);
        acc0 = __builtin_amdgcn_mfma_f32_16x16x32_bf16(al_0, bh, acc0, 0, 0, 0);
        acc1 = __builtin_amdgcn_mfma_f32_16x16x32_bf16(al_1, bh, acc1, 0, 0, 0);
    }

    const int col = n0 + wn + fr;
    #pragma unroll
    for (int mi = 0; mi < 2; ++mi) {
        f32x4 acc = mi ? acc1 : acc0;
        #pragma unroll
        for (int r = 0; r < 4; ++r) {
            const int row = m0 + wm + mi * 16 + fg * 4 + r;
            float val = __builtin_amdgcn_exp2f(acc[r] * C2LOG2E);
            if (!kside) {
                qpc[row * H + col] = val;
            } else {
                const int bb2 = row >> 8, kk = row & 255;
                kpc4[((bb2 * (H / 4) + (col >> 2)) * TK + kk) * 4 + (col & 3)] = val;
            }
        }
    }
}

// Fused scores + partial softmax + partial PV over a K-HALF.
// Block = (b, qgroup of 4, khalf), 512 threads, grid 1024 = 4 blocks/CU.
// Score: thread (kp = tid&63 -> 2 k-cols; hg = tid>>6 owns 32 h), with
//   software-pipelined kc loads (next h4 in flight during current compute).
// p stored TRANSPOSED pT[kk][q] so PV reads 1 broadcast ds_read_b128 per k.
// PV: thread owns 1 column, q-pair packed fma, unroll 8.
__global__ __launch_bounds__(512, 8)
void attn_kernel(const float* __restrict__ qpc, const float* __restrict__ kpc4,
                 const float* __restrict__ wv, const float* __restrict__ values,
                 float* __restrict__ opart, float* __restrict__ rs_g)
{
    __shared__ float qlds[H][QB];        // 4 KB [h][q] (eq)
    __shared__ float wlds[H];            // 1 KB
    __shared__ float accbuf[8][QB][128]; // 16 KB score partials (8 h-groups)
    __shared__ float pT[128][QB];        // 2 KB p transposed (this k-half)

    const int bid = blockIdx.x;
    const int b   = bid >> 7;
    const int qg  = (bid >> 1) & 63;
    const int kh  = bid & 1;
    const int q0  = qg * QB;
    const int tid = threadIdx.x;

    for (int i = tid; i < QB * H; i += 512) {
        const int h = i >> 2, q = i & 3;
        qlds[h][q] = qpc[(b * TQ + q0 + q) * H + h];
    }
    if (tid < H) wlds[tid] = wv[tid];
    __syncthreads();

    // ---- score: 2 k-columns (within half), 32 h per thread, pipelined ----
    {
        const int kp = tid & 63;             // k pair within half
        const int hg = tid >> 6;             // 0..7, 32 h each
        const int h0 = hg * 32;
        const float4* kc = (const float4*)kpc4 + (b * (H / 4) + hg * 8) * TK
                           + (kh * 128 + 2 * kp);
        v2f a01a = {0.f, 0.f}, a23a = {0.f, 0.f};   // k even: q01, q23
        v2f a01b = {0.f, 0.f}, a23b = {0.f, 0.f};   // k odd
        float4 kva4 = kc[0];                 // prefetch h4 = 0
        float4 kvb4 = kc[1];
        #pragma unroll
        for (int h4 = 0; h4 < 8; ++h4) {
            float4 nkva, nkvb;
            if (h4 < 7) {                    // issue next h4's loads early
                nkva = kc[(h4 + 1) * TK];
                nkvb = kc[(h4 + 1) * TK + 1];
            }
            float4 w4 = *(const float4*)&wlds[h0 + h4 * 4];
            #pragma unroll
            for (int j = 0; j < 4; ++j) {
                const int h = h0 + h4 * 4 + j;
                const float ea = (j == 0) ? kva4.x : (j == 1) ? kva4.y : (j == 2) ? kva4.z : kva4.w;
                const float eb = (j == 0) ? kvb4.x : (j == 1) ? kvb4.y : (j == 2) ? kvb4.z : kvb4.w;
                const float wj = (j == 0) ? w4.x  : (j == 1) ? w4.y  : (j == 2) ? w4.z  : w4.w;
                float4 qa = *(const float4*)&qlds[h][0];   // broadcast eq (4 q)
                v2f q01 = {qa.x, qa.y}, q23 = {qa.z, qa.w};
                v2f ea2 = {ea, ea}, eb2 = {eb, eb}, w2 = {wj, wj};
                v2f one = {1.0f, 1.0f};
                v2f d0a = __builtin_elementwise_fma(q01, ea2, one);  // eq*ek + 1
                v2f d1a = __builtin_elementwise_fma(q23, ea2, one);
                v2f d0b = __builtin_elementwise_fma(q01, eb2, one);
                v2f d1b = __builtin_elementwise_fma(q23, eb2, one);
                v2f r0a, r1a, r0b, r1b;
                r0a.x = __builtin_amdgcn_rcpf(d0a.x);
                r0a.y = __builtin_amdgcn_rcpf(d0a.y);
                r1a.x = __builtin_amdgcn_rcpf(d1a.x);
                r1a.y = __builtin_amdgcn_rcpf(d1a.y);
                r0b.x = __builtin_amdgcn_rcpf(d0b.x);
                r0b.y = __builtin_amdgcn_rcpf(d0b.y);
                r1b.x = __builtin_amdgcn_rcpf(d1b.x);
                r1b.y = __builtin_amdgcn_rcpf(d1b.y);
                a01a = __builtin_elementwise_fma(w2, r0a, a01a);
                a23a = __builtin_elementwise_fma(w2, r1a, a23a);
                a01b = __builtin_elementwise_fma(w2, r0b, a01b);
                a23b = __builtin_elementwise_fma(w2, r1b, a23b);
            }
            kva4 = nkva;
            kvb4 = nkvb;
        }
        accbuf[hg][0][2 * kp]     = a01a.x;
        accbuf[hg][1][2 * kp]     = a01a.y;
        accbuf[hg][2][2 * kp]     = a23a.x;
        accbuf[hg][3][2 * kp]     = a23a.y;
        accbuf[hg][0][2 * kp + 1] = a01b.x;
        accbuf[hg][1][2 * kp + 1] = a01b.y;
        accbuf[hg][2][2 * kp + 1] = a23b.x;
        accbuf[hg][3][2 * kp + 1] = a23b.y;
    }
    __syncthreads();

    // ---- combine 8 h-groups -> pT[kk][q] = exp2(-2log2e*acc) ----
    {
        const int q = tid >> 7, kl = tid & 127;
        float s = ((accbuf[0][q][kl] + accbuf[1][q][kl]) +
                   (accbuf[2][q][kl] + accbuf[3][q][kl])) +
                  ((accbuf[4][q][kl] + accbuf[5][q][kl]) +
                   (accbuf[6][q][kl] + accbuf[7][q][kl]));
        pT[kl][q] = __builtin_amdgcn_exp2f(s * NEG2LOG2E);
    }
    __syncthreads();

    // ---- partial rowsum (waves 0-3; global write, consumed by epilogue) ----
    {
        const int wave = tid >> 6, lane = tid & 63;
        if (wave < QB) {
            float s = pT[lane][wave] + pT[lane + 64][wave];
            #pragma unroll
            for (int off = 1; off < 64; off <<= 1)
                s += __shfl_xor(s, off);
            if (lane == 0) rs_g[(b * TQ + q0 + wave) * 2 + kh] = s;
        }
    }

    // ---- partial PV: thread owns column c; 128 k; q-pair packed ----
    {
        const int c = tid;
        const float* vb = values + (b * TK + kh * 128) * DV + c;
        v2f o01 = {0.f, 0.f}, o23 = {0.f, 0.f};
        #pragma unroll 8
        for (int kk = 0; kk < 128; ++kk) {
            float v = vb[kk * DV];
            float4 p4 = *(const float4*)&pT[kk][0];   // broadcast b128
            v2f vv = {v, v};
            v2f p01 = {p4.x, p4.y}, p23 = {p4.z, p4.w};
            o01 = __builtin_elementwise_fma(p01, vv, o01);
            o23 = __builtin_elementwise_fma(p23, vv, o23);
        }
        float* ob = opart + kh * (B * TQ * DV) + (b * TQ + q0) * DV + c;
        ob[0 * DV] = o01.x;
        ob[1 * DV] = o01.y;
        ob[2 * DV] = o23.x;
        ob[3 * DV] = o23.y;
    }
}

// out = (opart0 + opart1) * rcp(rs0 + rs1), float4 per thread.
__global__ __launch_bounds__(256)
void epilogue_kernel(const float* __restrict__ opart, const float* __restrict__ rs_g,
                     float* __restrict__ out)
{
    const int idx4 = blockIdx.x * 256 + threadIdx.x;     // f4 index, 262144 total
    const int row  = idx4 >> 7;                          // 128 f4 per row (DV=512)
    float rs = rs_g[2 * row] + rs_g[2 * row + 1];
    float inv = __builtin_amdgcn_rcpf(rs);
    const float4* o0 = (const float4*)opart;
    const float4* o1 = (const float4*)(opart + B * TQ * DV);
    float4 a = o0[idx4], bq = o1[idx4];
    float4 r;
    r.x = (a.x + bq.x) * inv;
    r.y = (a.y + bq.y) * inv;
    r.z = (a.z + bq.z) * inv;
    r.w = (a.w + bq.w) * inv;
    ((float4*)out)[idx4] = r;
}

extern "C" void kernel_launch(void* const* d_in, const int* in_sizes, int n_in,
                              void* d_out, int out_size, void* d_ws, size_t ws_size,
                              hipStream_t stream)
{
    const float* queries = (const float*)d_in[0];
    const float* keys    = (const float*)d_in[1];
    const float* values  = (const float*)d_in[2];
    const float* Wq      = (const float*)d_in[3];
    const float* Wk      = (const float*)d_in[4];
    const float* wv      = (const float*)d_in[5];
    float* out   = (float*)d_out;
    float* qpc   = (float*)d_ws;                   // (B*TQ, H)         2 MB (exp'd)
    float* kpc4  = qpc + B * TQ * H;               // (B, H/4, TK, 4)   2 MB (exp'd)
    float* opart = kpc4 + B * H * TK;              // [2][B*TQ, DV]     8 MB
    float* rs_g  = opart + 2 * B * TQ * DV;        // (B*TQ, 2)        16 KB

    dim3 gproj(B * TQ / 64, H / 32, 2);
    proj_kernel<<<gproj, 256, 0, stream>>>(queries, keys, Wq, Wk, qpc, kpc4);
    attn_kernel<<<B * (TQ / QB) * 2, 512, 0, stream>>>(qpc, kpc4, wv, values, opart, rs_g);
    epilogue_kernel<<<B * TQ * DV / 4 / 256, 256, 0, stream>>>(opart, rs_g, out);
}

// Round 15
// 49.511 us; speedup vs baseline: 1.1802x; 1.0065x over previous
//
#include <hip/hip_runtime.h>

typedef float v2f __attribute__((ext_vector_type(2)));
typedef short bf16x8 __attribute__((ext_vector_type(8)));
typedef float f32x4 __attribute__((ext_vector_type(4)));

namespace {
constexpr int B   = 8;
constexpr int TQ  = 256;
constexpr int TK  = 256;
constexpr int DQK = 512;
constexpr int DV  = 512;
constexpr int H   = 256;
constexpr int QB  = 4;           // q rows per attn block
constexpr float C2LOG2E   = 2.8853900817779268f;   // 2*log2(e)
constexpr float NEG2LOG2E = -2.8853900817779268f;
} // namespace

__device__ __forceinline__ uint32_t f2u(float x) { return __builtin_bit_cast(uint32_t, x); }
__device__ __forceinline__ float u2f(uint32_t x) { return __builtin_bit_cast(float, x); }
__device__ __forceinline__ uint32_t pack_hi(float x, float y) {
    return (f2u(y) & 0xFFFF0000u) | (f2u(x) >> 16);
}

// MFMA projections (bf16 hi/lo split), identical to R10/R13/R14.
__global__ __launch_bounds__(256)
void proj_kernel(const float* __restrict__ Q, const float* __restrict__ Kin,
                 const float* __restrict__ Wq, const float* __restrict__ Wk,
                 float* __restrict__ qpc, float* __restrict__ kpc4)
{
    __shared__ short Ahi[4][64][8];
    __shared__ short Alo[4][64][8];
    __shared__ short Bhi[4][32][8];
    __shared__ short Blo[4][32][8];

    const bool kside = (blockIdx.z == 1);
    const float* A = kside ? Kin : Q;
    const float* W = kside ? Wk  : Wq;
    const int m0 = blockIdx.x * 64;
    const int n0 = blockIdx.y * 32;
    const int tid = threadIdx.x;

    const int am = tid >> 2, ag = tid & 3;
    const int bk = tid >> 3, bn4 = (tid & 7) * 4;
    const float4* aptr = (const float4*)(A + (m0 + am) * DQK) + ag * 2;
    const float*  wptr = W + bk * H + n0 + bn4;

    const int w = tid >> 6, l = tid & 63;
    const int wm = (w >> 1) * 32, wn = (w & 1) * 16;
    const int fg = l >> 4;
    const int fr = l & 15;

    float4 a0 = aptr[0], a1 = aptr[1];
    float4 bv = *(const float4*)wptr;

    f32x4 acc0 = {0.f, 0.f, 0.f, 0.f};
    f32x4 acc1 = {0.f, 0.f, 0.f, 0.f};

    for (int s = 0; s < 16; ++s) {
        __syncthreads();
        {
            float ah0 = u2f(f2u(a0.x) & 0xFFFF0000u), ah1 = u2f(f2u(a0.y) & 0xFFFF0000u);
            float ah2 = u2f(f2u(a0.z) & 0xFFFF0000u), ah3 = u2f(f2u(a0.w) & 0xFFFF0000u);
            float ah4 = u2f(f2u(a1.x) & 0xFFFF0000u), ah5 = u2f(f2u(a1.y) & 0xFFFF0000u);
            float ah6 = u2f(f2u(a1.z) & 0xFFFF0000u), ah7 = u2f(f2u(a1.w) & 0xFFFF0000u);
            int4 hw, lw;
            hw.x = (int)pack_hi(a0.x, a0.y); hw.y = (int)pack_hi(a0.z, a0.w);
            hw.z = (int)pack_hi(a1.x, a1.y); hw.w = (int)pack_hi(a1.z, a1.w);
            lw.x = (int)pack_hi(a0.x - ah0, a0.y - ah1);
            lw.y = (int)pack_hi(a0.z - ah2, a0.w - ah3);
            lw.z = (int)pack_hi(a1.x - ah4, a1.y - ah5);
            lw.w = (int)pack_hi(a1.z - ah6, a1.w - ah7);
            *(int4*)&Ahi[ag][am][0] = hw;
            *(int4*)&Alo[ag][am][0] = lw;
            const int g = bk >> 3, slot = bk & 7;
            float bb[4] = {bv.x, bv.y, bv.z, bv.w};
            #pragma unroll
            for (int i = 0; i < 4; ++i) {
                uint32_t u = f2u(bb[i]);
                float hf = u2f(u & 0xFFFF0000u);
                Bhi[g][bn4 + i][slot] = (short)(u >> 16);
                Blo[g][bn4 + i][slot] = (short)(f2u(bb[i] - hf) >> 16);
            }
        }
        __syncthreads();
        if (s < 15) {
            a0 = aptr[s * 8 + 8];
            a1 = aptr[s * 8 + 9];
            bv = *(const float4*)(wptr + (s + 1) * 32 * H);
        }
        bf16x8 ah_0 = *(const bf16x8*)&Ahi[fg][wm + fr][0];
        bf16x8 ah_1 = *(const bf16x8*)&Ahi[fg][wm + 16 + fr][0];
        bf16x8 al_0 = *(const bf16x8*)&Alo[fg][wm + fr][0];
        bf16x8 al_1 = *(const bf16x8*)&Alo[fg][wm + 16 + fr][0];
        bf16x8 bh   = *(const bf16x8*)&Bhi[fg][wn + fr][0];
        bf16x8 bl   = *(const bf16x8*)&Blo[fg][wn + fr][0];
        acc0 = __builtin_amdgcn_mfma_f32_16x16x32_bf16(ah_0, bh, acc0, 0, 0, 0);
        acc1 = __builtin_amdgcn_mfma_f32_16x16x32_bf16(ah_1, bh, acc1, 0, 0, 0);
        acc0 = __builtin_amdgcn_mfma_f32_16x16x32_bf16(ah_0, bl, acc0, 0, 0, 0);
        acc1 = __builtin_amdgcn_mfma_f32_16x16x32_bf16(ah_1, bl, acc1, 0, 0, 0);
        acc0 = __builtin_amdgcn_mfma_f32_16x16x32_bf16(al_0, bh, acc0, 0, 0, 0);
        acc1 = __builtin_amdgcn_mfma_f32_16x16x32_bf16(al_1, bh, acc1, 0, 0, 0);
    }

    const int col = n0 + wn + fr;
    #pragma unroll
    for (int mi = 0; mi < 2; ++mi) {
        f32x4 acc = mi ? acc1 : acc0;
        #pragma unroll
        for (int r = 0; r < 4; ++r) {
            const int row = m0 + wm + mi * 16 + fg * 4 + r;
            float val = __builtin_amdgcn_exp2f(acc[r] * C2LOG2E);
            if (!kside) {
                qpc[row * H + col] = val;
            } else {
                const int bb2 = row >> 8, kk = row & 255;
                kpc4[((bb2 * (H / 4) + (col >> 2)) * TK + kk) * 4 + (col & 3)] = val;
            }
        }
    }
}

// Fused scores + partial softmax + partial PV over a K-HALF (R14 structure).
// Score now uses h-PAIRING: w0/d0 + w1/d1 = (w0*d1 + w1*d0) * rcp(d0*d1) —
// one rcp per TWO elements (was one per element). den = d0*d1 <= ~1e26, safe.
__global__ __launch_bounds__(512, 8)
void attn_kernel(const float* __restrict__ qpc, const float* __restrict__ kpc4,
                 const float* __restrict__ wv, const float* __restrict__ values,
                 float* __restrict__ opart, float* __restrict__ rs_g)
{
    __shared__ float qlds[H][QB];        // 4 KB [h][q] (eq)
    __shared__ float wlds[H];            // 1 KB
    __shared__ float accbuf[8][QB][128]; // 16 KB score partials (8 h-groups)
    __shared__ float pT[128][QB];        // 2 KB p transposed (this k-half)

    const int bid = blockIdx.x;
    const int b   = bid >> 7;
    const int qg  = (bid >> 1) & 63;
    const int kh  = bid & 1;
    const int q0  = qg * QB;
    const int tid = threadIdx.x;

    for (int i = tid; i < QB * H; i += 512) {
        const int h = i >> 2, q = i & 3;
        qlds[h][q] = qpc[(b * TQ + q0 + q) * H + h];
    }
    if (tid < H) wlds[tid] = wv[tid];
    __syncthreads();

    // ---- score: 2 k-columns (within half), 32 h per thread, h-paired rcp ----
    {
        const int kp = tid & 63;             // k pair within half
        const int hg = tid >> 6;             // 0..7, 32 h each
        const int h0 = hg * 32;
        const float4* kc = (const float4*)kpc4 + (b * (H / 4) + hg * 8) * TK
                           + (kh * 128 + 2 * kp);
        v2f a01a = {0.f, 0.f}, a23a = {0.f, 0.f};   // k even: q01, q23
        v2f a01b = {0.f, 0.f}, a23b = {0.f, 0.f};   // k odd
        const v2f one = {1.0f, 1.0f};
        float4 kva4 = kc[0];                 // prefetch h4 = 0
        float4 kvb4 = kc[1];
        #pragma unroll
        for (int h4 = 0; h4 < 8; ++h4) {
            float4 nkva, nkvb;
            if (h4 < 7) {                    // issue next h4's loads early
                nkva = kc[(h4 + 1) * TK];
                nkvb = kc[(h4 + 1) * TK + 1];
            }
            float4 w4 = *(const float4*)&wlds[h0 + h4 * 4];
            #pragma unroll
            for (int hp = 0; hp < 2; ++hp) {    // h-pairs (4h4+2hp, 4h4+2hp+1)
                const int h = h0 + h4 * 4 + hp * 2;
                const float ea0 = hp ? kva4.z : kva4.x;
                const float ea1 = hp ? kva4.w : kva4.y;
                const float eb0 = hp ? kvb4.z : kvb4.x;
                const float eb1 = hp ? kvb4.w : kvb4.y;
                const float w0s = hp ? w4.z : w4.x;
                const float w1s = hp ? w4.w : w4.y;
                float4 qh0 = *(const float4*)&qlds[h][0];     // eq, 4 q, h
                float4 qh1 = *(const float4*)&qlds[h + 1][0]; // eq, 4 q, h+1
                v2f q01_0 = {qh0.x, qh0.y}, q23_0 = {qh0.z, qh0.w};
                v2f q01_1 = {qh1.x, qh1.y}, q23_1 = {qh1.z, qh1.w};
                v2f w0v = {w0s, w0s}, w1v = {w1s, w1s};
                v2f ea0v = {ea0, ea0}, ea1v = {ea1, ea1};
                v2f eb0v = {eb0, eb0}, eb1v = {eb1, eb1};
                // ---- k even, q01 ----
                {
                    v2f d0 = __builtin_elementwise_fma(q01_0, ea0v, one);
                    v2f d1 = __builtin_elementwise_fma(q01_1, ea1v, one);
                    v2f n  = __builtin_elementwise_fma(w1v, d0, w0v * d1);
                    v2f den = d0 * d1;
                    v2f r;
                    r.x = __builtin_amdgcn_rcpf(den.x);
                    r.y = __builtin_amdgcn_rcpf(den.y);
                    a01a = __builtin_elementwise_fma(n, r, a01a);
                }
                // ---- k even, q23 ----
                {
                    v2f d0 = __builtin_elementwise_fma(q23_0, ea0v, one);
                    v2f d1 = __builtin_elementwise_fma(q23_1, ea1v, one);
                    v2f n  = __builtin_elementwise_fma(w1v, d0, w0v * d1);
                    v2f den = d0 * d1;
                    v2f r;
                    r.x = __builtin_amdgcn_rcpf(den.x);
                    r.y = __builtin_amdgcn_rcpf(den.y);
                    a23a = __builtin_elementwise_fma(n, r, a23a);
                }
                // ---- k odd, q01 ----
                {
                    v2f d0 = __builtin_elementwise_fma(q01_0, eb0v, one);
                    v2f d1 = __builtin_elementwise_fma(q01_1, eb1v, one);
                    v2f n  = __builtin_elementwise_fma(w1v, d0, w0v * d1);
                    v2f den = d0 * d1;
                    v2f r;
                    r.x = __builtin_amdgcn_rcpf(den.x);
                    r.y = __builtin_amdgcn_rcpf(den.y);
                    a01b = __builtin_elementwise_fma(n, r, a01b);
                }
                // ---- k odd, q23 ----
                {
                    v2f d0 = __builtin_elementwise_fma(q23_0, eb0v, one);
                    v2f d1 = __builtin_elementwise_fma(q23_1, eb1v, one);
                    v2f n  = __builtin_elementwise_fma(w1v, d0, w0v * d1);
                    v2f den = d0 * d1;
                    v2f r;
                    r.x = __builtin_amdgcn_rcpf(den.x);
                    r.y = __builtin_amdgcn_rcpf(den.y);
                    a23b = __builtin_elementwise_fma(n, r, a23b);
                }
            }
            kva4 = nkva;
            kvb4 = nkvb;
        }
        accbuf[hg][0][2 * kp]     = a01a.x;
        accbuf[hg][1][2 * kp]     = a01a.y;
        accbuf[hg][2][2 * kp]     = a23a.x;
        accbuf[hg][3][2 * kp]     = a23a.y;
        accbuf[hg][0][2 * kp + 1] = a01b.x;
        accbuf[hg][1][2 * kp + 1] = a01b.y;
        accbuf[hg][2][2 * kp + 1] = a23b.x;
        accbuf[hg][3][2 * kp + 1] = a23b.y;
    }
    __syncthreads();

    // ---- combine 8 h-groups -> pT[kk][q] = exp2(-2log2e*acc) ----
    {
        const int q = tid >> 7, kl = tid & 127;
        float s = ((accbuf[0][q][kl] + accbuf[1][q][kl]) +
                   (accbuf[2][q][kl] + accbuf[3][q][kl])) +
                  ((accbuf[4][q][kl] + accbuf[5][q][kl]) +
                   (accbuf[6][q][kl] + accbuf[7][q][kl]));
        pT[kl][q] = __builtin_amdgcn_exp2f(s * NEG2LOG2E);
    }
    __syncthreads();

    // ---- partial rowsum (waves 0-3; global write, consumed by epilogue) ----
    {
        const int wave = tid >> 6, lane = tid & 63;
        if (wave < QB) {
            float s = pT[lane][wave] + pT[lane + 64][wave];
            #pragma unroll
            for (int off = 1; off < 64; off <<= 1)
                s += __shfl_xor(s, off);
            if (lane == 0) rs_g[(b * TQ + q0 + wave) * 2 + kh] = s;
        }
    }

    // ---- partial PV: thread owns column c; 128 k; q-pair packed ----
    {
        const int c = tid;
        const float* vb = values + (b * TK + kh * 128) * DV + c;
        v2f o01 = {0.f, 0.f}, o23 = {0.f, 0.f};
        #pragma unroll 8
        for (int kk = 0; kk < 128; ++kk) {
            float v = vb[kk * DV];
            float4 p4 = *(const float4*)&pT[kk][0];   // broadcast b128
            v2f vv = {v, v};
            v2f p01 = {p4.x, p4.y}, p23 = {p4.z, p4.w};
            o01 = __builtin_elementwise_fma(p01, vv, o01);
            o23 = __builtin_elementwise_fma(p23, vv, o23);
        }
        float* ob = opart + kh * (B * TQ * DV) + (b * TQ + q0) * DV + c;
        ob[0 * DV] = o01.x;
        ob[1 * DV] = o01.y;
        ob[2 * DV] = o23.x;
        ob[3 * DV] = o23.y;
    }
}

// out = (opart0 + opart1) * rcp(rs0 + rs1), float4 per thread.
__global__ __launch_bounds__(256)
void epilogue_kernel(const float* __restrict__ opart, const float* __restrict__ rs_g,
                     float* __restrict__ out)
{
    const int idx4 = blockIdx.x * 256 + threadIdx.x;     // f4 index, 262144 total
    const int row  = idx4 >> 7;                          // 128 f4 per row (DV=512)
    float rs = rs_g[2 * row] + rs_g[2 * row + 1];
    float inv = __builtin_amdgcn_rcpf(rs);
    const float4* o0 = (const float4*)opart;
    const float4* o1 = (const float4*)(opart + B * TQ * DV);
    float4 a = o0[idx4], bq = o1[idx4];
    float4 r;
    r.x = (a.x + bq.x) * inv;
    r.y = (a.y + bq.y) * inv;
    r.z = (a.z + bq.z) * inv;
    r.w = (a.w + bq.w) * inv;
    ((float4*)out)[idx4] = r;
}

extern "C" void kernel_launch(void* const* d_in, const int* in_sizes, int n_in,
                              void* d_out, int out_size, void* d_ws, size_t ws_size,
                              hipStream_t stream)
{
    const float* queries = (const float*)d_in[0];
    const float* keys    = (const float*)d_in[1];
    const float* values  = (const float*)d_in[2];
    const float* Wq      = (const float*)d_in[3];
    const float* Wk      = (const float*)d_in[4];
    const float* wv      = (const float*)d_in[5];
    float* out   = (float*)d_out;
    float* qpc   = (float*)d_ws;                   // (B*TQ, H)         2 MB (exp'd)
    float* kpc4  = qpc + B * TQ * H;               // (B, H/4, TK, 4)   2 MB (exp'd)
    float* opart = kpc4 + B * H * TK;              // [2][B*TQ, DV]     8 MB
    float* rs_g  = opart + 2 * B * TQ * DV;        // (B*TQ, 2)        16 KB

    dim3 gproj(B * TQ / 64, H / 32, 2);
    proj_kernel<<<gproj, 256, 0, stream>>>(queries, keys, Wq, Wk, qpc, kpc4);
    attn_kernel<<<B * (TQ / QB) * 2, 512, 0, stream>>>(qpc, kpc4, wv, values, opart, rs_g);
    epilogue_kernel<<<B * TQ * DV / 4 / 256, 256, 0, stream>>>(opart, rs_g, out);
}

// Round 16
// 49.038 us; speedup vs baseline: 1.1916x; 1.0096x over previous
//
#include <hip/hip_runtime.h>

typedef float v2f __attribute__((ext_vector_type(2)));
typedef short bf16x8 __attribute__((ext_vector_type(8)));
typedef float f32x4 __attribute__((ext_vector_type(4)));

namespace {
constexpr int B   = 8;
constexpr int TQ  = 256;
constexpr int TK  = 256;
constexpr int DQK = 512;
constexpr int DV  = 512;
constexpr int H   = 256;
constexpr int QB  = 8;           // q rows per attn block
constexpr float C2LOG2E   = 2.8853900817779268f;   // 2*log2(e)
constexpr float NEG2LOG2E = -2.8853900817779268f;
} // namespace

__device__ __forceinline__ uint32_t f2u(float x) { return __builtin_bit_cast(uint32_t, x); }
__device__ __forceinline__ float u2f(uint32_t x) { return __builtin_bit_cast(float, x); }
__device__ __forceinline__ uint32_t pack_hi(float x, float y) {
    return (f2u(y) & 0xFFFF0000u) | (f2u(x) >> 16);
}

// MFMA projections (bf16 hi/lo split), identical to R10..R15.
__global__ __launch_bounds__(256)
void proj_kernel(const float* __restrict__ Q, const float* __restrict__ Kin,
                 const float* __restrict__ Wq, const float* __restrict__ Wk,
                 float* __restrict__ qpc, float* __restrict__ kpc4)
{
    __shared__ short Ahi[4][64][8];
    __shared__ short Alo[4][64][8];
    __shared__ short Bhi[4][32][8];
    __shared__ short Blo[4][32][8];

    const bool kside = (blockIdx.z == 1);
    const float* A = kside ? Kin : Q;
    const float* W = kside ? Wk  : Wq;
    const int m0 = blockIdx.x * 64;
    const int n0 = blockIdx.y * 32;
    const int tid = threadIdx.x;

    const int am = tid >> 2, ag = tid & 3;
    const int bk = tid >> 3, bn4 = (tid & 7) * 4;
    const float4* aptr = (const float4*)(A + (m0 + am) * DQK) + ag * 2;
    const float*  wptr = W + bk * H + n0 + bn4;

    const int w = tid >> 6, l = tid & 63;
    const int wm = (w >> 1) * 32, wn = (w & 1) * 16;
    const int fg = l >> 4;
    const int fr = l & 15;

    float4 a0 = aptr[0], a1 = aptr[1];
    float4 bv = *(const float4*)wptr;

    f32x4 acc0 = {0.f, 0.f, 0.f, 0.f};
    f32x4 acc1 = {0.f, 0.f, 0.f, 0.f};

    for (int s = 0; s < 16; ++s) {
        __syncthreads();
        {
            float ah0 = u2f(f2u(a0.x) & 0xFFFF0000u), ah1 = u2f(f2u(a0.y) & 0xFFFF0000u);
            float ah2 = u2f(f2u(a0.z) & 0xFFFF0000u), ah3 = u2f(f2u(a0.w) & 0xFFFF0000u);
            float ah4 = u2f(f2u(a1.x) & 0xFFFF0000u), ah5 = u2f(f2u(a1.y) & 0xFFFF0000u);
            float ah6 = u2f(f2u(a1.z) & 0xFFFF0000u), ah7 = u2f(f2u(a1.w) & 0xFFFF0000u);
            int4 hw, lw;
            hw.x = (int)pack_hi(a0.x, a0.y); hw.y = (int)pack_hi(a0.z, a0.w);
            hw.z = (int)pack_hi(a1.x, a1.y); hw.w = (int)pack_hi(a1.z, a1.w);
            lw.x = (int)pack_hi(a0.x - ah0, a0.y - ah1);
            lw.y = (int)pack_hi(a0.z - ah2, a0.w - ah3);
            lw.z = (int)pack_hi(a1.x - ah4, a1.y - ah5);
            lw.w = (int)pack_hi(a1.z - ah6, a1.w - ah7);
            *(int4*)&Ahi[ag][am][0] = hw;
            *(int4*)&Alo[ag][am][0] = lw;
            const int g = bk >> 3, slot = bk & 7;
            float bb[4] = {bv.x, bv.y, bv.z, bv.w};
            #pragma unroll
            for (int i = 0; i < 4; ++i) {
                uint32_t u = f2u(bb[i]);
                float hf = u2f(u & 0xFFFF0000u);
                Bhi[g][bn4 + i][slot] = (short)(u >> 16);
                Blo[g][bn4 + i][slot] = (short)(f2u(bb[i] - hf) >> 16);
            }
        }
        __syncthreads();
        if (s < 15) {
            a0 = aptr[s * 8 + 8];
            a1 = aptr[s * 8 + 9];
            bv = *(const float4*)(wptr + (s + 1) * 32 * H);
        }
        bf16x8 ah_0 = *(const bf16x8*)&Ahi[fg][wm + fr][0];
        bf16x8 ah_1 = *(const bf16x8*)&Ahi[fg][wm + 16 + fr][0];
        bf16x8 al_0 = *(const bf16x8*)&Alo[fg][wm + fr][0];
        bf16x8 al_1 = *(const bf16x8*)&Alo[fg][wm + 16 + fr][0];
        bf16x8 bh   = *(const bf16x8*)&Bhi[fg][wn + fr][0];
        bf16x8 bl   = *(const bf16x8*)&Blo[fg][wn + fr][0];
        acc0 = __builtin_amdgcn_mfma_f32_16x16x32_bf16(ah_0, bh, acc0, 0, 0, 0);
        acc1 = __builtin_amdgcn_mfma_f32_16x16x32_bf16(ah_1, bh, acc1, 0, 0, 0);
        acc0 = __builtin_amdgcn_mfma_f32_16x16x32_bf16(ah_0, bl, acc0, 0, 0, 0);
        acc1 = __builtin_amdgcn_mfma_f32_16x16x32_bf16(ah_1, bl, acc1, 0, 0, 0);
        acc0 = __builtin_amdgcn_mfma_f32_16x16x32_bf16(al_0, bh, acc0, 0, 0, 0);
        acc1 = __builtin_amdgcn_mfma_f32_16x16x32_bf16(al_1, bh, acc1, 0, 0, 0);
    }

    const int col = n0 + wn + fr;
    #pragma unroll
    for (int mi = 0; mi < 2; ++mi) {
        f32x4 acc = mi ? acc1 : acc0;
        #pragma unroll
        for (int r = 0; r < 4; ++r) {
            const int row = m0 + wm + mi * 16 + fg * 4 + r;
            float val = __builtin_amdgcn_exp2f(acc[r] * C2LOG2E);
            if (!kside) {
                qpc[row * H + col] = val;
            } else {
                const int bb2 = row >> 8, kk = row & 255;
                kpc4[((bb2 * (H / 4) + (col >> 2)) * TK + kk) * 4 + (col & 3)] = val;
            }
        }
    }
}

// Fused scores + partial softmax + partial PV over a K-HALF, QB=8.
// Block = (b, qgroup of 8, khalf), 512 threads, grid 512 = 2 blocks/CU.
// Score: thread = (kp = tid&127 -> ONE k; hg = tid>>7 owns 64 h). One kc
//   float4 per h4 (16 total, evenly spaced -> deep prefetch under 128-VGPR cap).
// PV: thread owns 1 column, 8 q outputs, q-pair packed fma.
__global__ __launch_bounds__(512, 4)
void attn_kernel(const float* __restrict__ qpc, const float* __restrict__ kpc4,
                 const float* __restrict__ wv, const float* __restrict__ values,
                 float* __restrict__ opart, float* __restrict__ rs_g)
{
    __shared__ float qlds[H][QB];        // 8 KB [h][q] (eq)
    __shared__ float wlds[H];            // 1 KB
    __shared__ float accbuf[4][QB][128]; // 16 KB score partials (4 h-groups)
    __shared__ float pT[128][QB];        // 4 KB p transposed (this k-half)

    const int bid = blockIdx.x;
    const int b   = bid >> 6;
    const int qg  = (bid >> 1) & 31;
    const int kh  = bid & 1;
    const int q0  = qg * QB;
    const int tid = threadIdx.x;

    for (int i = tid; i < QB * H; i += 512) {
        const int h = i >> 3, q = i & 7;
        qlds[h][q] = qpc[(b * TQ + q0 + q) * H + h];
    }
    if (tid < H) wlds[tid] = wv[tid];
    __syncthreads();

    // ---- score: ONE k-column, 64 h per thread, pipelined kc loads ----
    {
        const int kp = tid & 127;            // k within half
        const int hg = tid >> 7;             // 0..3, 64 h each
        const int h0 = hg * 64;
        const float4* kc = (const float4*)kpc4 + (b * (H / 4) + hg * 16) * TK
                           + (kh * 128 + kp);
        v2f a01 = {0.f, 0.f}, a23 = {0.f, 0.f};
        v2f a45 = {0.f, 0.f}, a67 = {0.f, 0.f};
        const v2f one = {1.0f, 1.0f};
        float4 kv = kc[0];                   // prefetch h4 = 0
        #pragma unroll
        for (int h4 = 0; h4 < 16; ++h4) {
            float4 nkv;
            if (h4 < 15) nkv = kc[(h4 + 1) * TK];   // next h4 in flight
            float4 w4 = *(const float4*)&wlds[h0 + h4 * 4];
            #pragma unroll
            for (int j = 0; j < 4; ++j) {
                const int h = h0 + h4 * 4 + j;
                const float ek = (j == 0) ? kv.x : (j == 1) ? kv.y : (j == 2) ? kv.z : kv.w;
                const float wj = (j == 0) ? w4.x : (j == 1) ? w4.y : (j == 2) ? w4.z : w4.w;
                float4 qa = *(const float4*)&qlds[h][0];   // broadcast eq q0..3
                float4 qb = *(const float4*)&qlds[h][4];   // broadcast eq q4..7
                v2f ek2 = {ek, ek}, w2 = {wj, wj};
                v2f qp0 = {qa.x, qa.y}, qp1 = {qa.z, qa.w};
                v2f qp2 = {qb.x, qb.y}, qp3 = {qb.z, qb.w};
                v2f d0 = __builtin_elementwise_fma(qp0, ek2, one);
                v2f d1 = __builtin_elementwise_fma(qp1, ek2, one);
                v2f d2 = __builtin_elementwise_fma(qp2, ek2, one);
                v2f d3 = __builtin_elementwise_fma(qp3, ek2, one);
                v2f r0, r1, r2, r3;
                r0.x = __builtin_amdgcn_rcpf(d0.x);
                r0.y = __builtin_amdgcn_rcpf(d0.y);
                r1.x = __builtin_amdgcn_rcpf(d1.x);
                r1.y = __builtin_amdgcn_rcpf(d1.y);
                r2.x = __builtin_amdgcn_rcpf(d2.x);
                r2.y = __builtin_amdgcn_rcpf(d2.y);
                r3.x = __builtin_amdgcn_rcpf(d3.x);
                r3.y = __builtin_amdgcn_rcpf(d3.y);
                a01 = __builtin_elementwise_fma(w2, r0, a01);
                a23 = __builtin_elementwise_fma(w2, r1, a23);
                a45 = __builtin_elementwise_fma(w2, r2, a45);
                a67 = __builtin_elementwise_fma(w2, r3, a67);
            }
            kv = nkv;
        }
        accbuf[hg][0][kp] = a01.x;
        accbuf[hg][1][kp] = a01.y;
        accbuf[hg][2][kp] = a23.x;
        accbuf[hg][3][kp] = a23.y;
        accbuf[hg][4][kp] = a45.x;
        accbuf[hg][5][kp] = a45.y;
        accbuf[hg][6][kp] = a67.x;
        accbuf[hg][7][kp] = a67.y;
    }
    __syncthreads();

    // ---- combine 4 h-groups -> pT[kk][q] = exp2(-2log2e*acc) ----
    for (int i = tid; i < QB * 128; i += 512) {
        const int q = i >> 7, kl = i & 127;
        float s = (accbuf[0][q][kl] + accbuf[1][q][kl]) +
                  (accbuf[2][q][kl] + accbuf[3][q][kl]);
        pT[kl][q] = __builtin_amdgcn_exp2f(s * NEG2LOG2E);
    }
    __syncthreads();

    // ---- partial rowsum: wave w (0..7) reduces row q=w ----
    {
        const int wave = tid >> 6, lane = tid & 63;
        float s = pT[lane][wave] + pT[lane + 64][wave];
        #pragma unroll
        for (int off = 1; off < 64; off <<= 1)
            s += __shfl_xor(s, off);
        if (lane == 0) rs_g[(b * TQ + q0 + wave) * 2 + kh] = s;
    }

    // ---- partial PV: thread owns column c; 128 k; q-pair packed ----
    {
        const int c = tid;
        const float* vb = values + (b * TK + kh * 128) * DV + c;
        v2f o01 = {0.f, 0.f}, o23 = {0.f, 0.f};
        v2f o45 = {0.f, 0.f}, o67 = {0.f, 0.f};
        #pragma unroll 8
        for (int kk = 0; kk < 128; ++kk) {
            float v = vb[kk * DV];
            float4 p4a = *(const float4*)&pT[kk][0];   // broadcast b128
            float4 p4b = *(const float4*)&pT[kk][4];
            v2f vv = {v, v};
            o01 = __builtin_elementwise_fma((v2f){p4a.x, p4a.y}, vv, o01);
            o23 = __builtin_elementwise_fma((v2f){p4a.z, p4a.w}, vv, o23);
            o45 = __builtin_elementwise_fma((v2f){p4b.x, p4b.y}, vv, o45);
            o67 = __builtin_elementwise_fma((v2f){p4b.z, p4b.w}, vv, o67);
        }
        float* ob = opart + kh * (B * TQ * DV) + (b * TQ + q0) * DV + c;
        ob[0 * DV] = o01.x;
        ob[1 * DV] = o01.y;
        ob[2 * DV] = o23.x;
        ob[3 * DV] = o23.y;
        ob[4 * DV] = o45.x;
        ob[5 * DV] = o45.y;
        ob[6 * DV] = o67.x;
        ob[7 * DV] = o67.y;
    }
}

// out = (opart0 + opart1) * rcp(rs0 + rs1), float4 per thread.
__global__ __launch_bounds__(256)
void epilogue_kernel(const float* __restrict__ opart, const float* __restrict__ rs_g,
                     float* __restrict__ out)
{
    const int idx4 = blockIdx.x * 256 + threadIdx.x;     // f4 index, 262144 total
    const int row  = idx4 >> 7;                          // 128 f4 per row (DV=512)
    float rs = rs_g[2 * row] + rs_g[2 * row + 1];
    float inv = __builtin_amdgcn_rcpf(rs);
    const float4* o0 = (const float4*)opart;
    const float4* o1 = (const float4*)(opart + B * TQ * DV);
    float4 a = o0[idx4], bq = o1[idx4];
    float4 r;
    r.x = (a.x + bq.x) * inv;
    r.y = (a.y + bq.y) * inv;
    r.z = (a.z + bq.z) * inv;
    r.w = (a.w + bq.w) * inv;
    ((float4*)out)[idx4] = r;
}

extern "C" void kernel_launch(void* const* d_in, const int* in_sizes, int n_in,
                              void* d_out, int out_size, void* d_ws, size_t ws_size,
                              hipStream_t stream)
{
    const float* queries = (const float*)d_in[0];
    const float* keys    = (const float*)d_in[1];
    const float* values  = (const float*)d_in[2];
    const float* Wq      = (const float*)d_in[3];
    const float* Wk      = (const float*)d_in[4];
    const float* wv      = (const float*)d_in[5];
    float* out   = (float*)d_out;
    float* qpc   = (float*)d_ws;                   // (B*TQ, H)         2 MB (exp'd)
    float* kpc4  = qpc + B * TQ * H;               // (B, H/4, TK, 4)   2 MB (exp'd)
    float* opart = kpc4 + B * H * TK;              // [2][B*TQ, DV]     8 MB
    float* rs_g  = opart + 2 * B * TQ * DV;        // (B*TQ, 2)        16 KB

    dim3 gproj(B * TQ / 64, H / 32, 2);
    proj_kernel<<<gproj, 256, 0, stream>>>(queries, keys, Wq, Wk, qpc, kpc4);
    attn_kernel<<<B * (TQ / QB) * 2, 512, 0, stream>>>(qpc, kpc4, wv, values, opart, rs_g);
    epilogue_kernel<<<B * TQ * DV / 4 / 256, 256, 0, stream>>>(opart, rs_g, out);
}